// Round 4
// baseline (889.329 us; speedup 1.0000x reference)
//
#include <hip/hip_runtime.h>

namespace {

constexpr int T = 64;      // tags
constexpr int S = 512;     // sequence length
constexpr int B = 32;      // batch
constexpr int DEPTH = 6;   // LDS prefetch ring depth (vmcnt(4*(DEPTH-1)) = 20)

#define WAIT_VM20() asm volatile("s_waitcnt vmcnt(20)" ::: "memory")
#define WAIT_VM0()  asm volatile("s_waitcnt vmcnt(0)" ::: "memory")
#define WAIT_LGKM() asm volatile("s_waitcnt lgkmcnt(0)" ::: "memory")
#define CBAR()      asm volatile("" ::: "memory")

__device__ __forceinline__ void load16(const float* g, float* l) {
  // async global->LDS, 16 B per lane; LDS dst = uniform base + lane*16
  __builtin_amdgcn_global_load_lds(
      (const __attribute__((address_space(1))) void*)g,
      (__attribute__((address_space(3))) void*)l, 16, 0, 0);
}

// order-preserving float->uint (monotone), and inverse
__device__ __forceinline__ unsigned int f2s(float f) {
  unsigned int u = __float_as_uint(f);
  return u ^ (unsigned int)(((int)u >> 31) | 0x80000000);
}
__device__ __forceinline__ float s2f(unsigned int u) {
  u ^= (u & 0x80000000u) ? 0x80000000u : 0xFFFFFFFFu;
  return __uint_as_float(u);
}

__global__ __launch_bounds__(256, 1) void viterbi_fwd(
    const float* __restrict__ P,
    const int* __restrict__ mask,   // bool input is uploaded as int32 (1/0)
    int* __restrict__ out)
{
  // 96 KB ring + 0.5 KB alpha + 2 KB partials + 32 KB backpointers = 130.7 KB (gfx950 LDS = 160 KB)
  __shared__ __align__(16) float lds_p[DEPTH * T * T];
  __shared__ __align__(16) float lds_alpha[2][T];
  __shared__ __align__(16) unsigned long long lds_part[4][T];
  __shared__ __align__(16) unsigned char lds_bp[S * T];

  const int tid = threadIdx.x;
  const int j   = tid & 63;          // column owned for partials
  const int w   = tid >> 6;          // wave id; owns rows [16w, 16w+16)
  const int b   = blockIdx.x;
  const float* Pb = P + (size_t)b * S * T * T;

  if (tid < T) lds_alpha[0][tid] = 0.0f;   // free initial prev tag: alpha_in = 0

  // prologue: issue DEPTH step-tiles; each wave DMAs only its own quarter
  for (int d = 0; d < DEPTH; ++d) {
    const float* gs = Pb + d * (T * T) + w * 1024 + j * 4;
    float* ls = &lds_p[d * (T * T) + w * 1024];
#pragma unroll
    for (int r = 0; r < 4; ++r) load16(gs + r * 256, ls + r * 256);
  }
  WAIT_LGKM(); __builtin_amdgcn_s_barrier(); CBAR();  // alpha init visible

  float last_alpha = 0.0f;
  int slot = 0;
  int next_src = DEPTH;

  for (int s = 0; s < S; ++s) {
    // own quarter of tile s is resident after this (oldest 4 of 24 in-flight)
    WAIT_VM20();

    // alpha for my 16 rows (uniform per wave -> broadcast reads)
    float a[16];
    {
      const float4* ap = (const float4*)&lds_alpha[s & 1][w * 16];
#pragma unroll
      for (int r = 0; r < 4; ++r) {
        float4 v = ap[r];
        a[4 * r + 0] = v.x; a[4 * r + 1] = v.y;
        a[4 * r + 2] = v.z; a[4 * r + 3] = v.w;
      }
    }

    // scan 16 rows of column j; strict > keeps first index (ties -> smallest i)
    const float* pb = &lds_p[slot * (T * T) + w * 1024 + j];
    float best = a[0] + pb[0];
    int bi = w * 16;
#pragma unroll
    for (int k = 1; k < 16; ++k) {
      float sc = a[k] + pb[k * 64];
      bool g = sc > best;
      bi   = g ? (w * 16 + k) : bi;
      best = g ? sc : best;
    }

    // packed partial: max picks larger score; tie -> larger (255-i) = smaller i
    lds_part[w][j] = ((unsigned long long)f2s(best) << 32) | (unsigned int)(255 - bi);
    WAIT_LGKM(); __builtin_amdgcn_s_barrier(); CBAR();

    // combine 4 wave-partials (redundant across waves; broadcast reads)
    unsigned long long m = lds_part[0][j];
#pragma unroll
    for (int q = 1; q < 4; ++q) {
      unsigned long long t2 = lds_part[q][j];
      m = (t2 > m) ? t2 : m;
    }
    last_alpha = s2f((unsigned int)(m >> 32));
    const int bnew = 255 - (int)(m & 0xFFu);
    if (w == 0) {
      lds_alpha[(s + 1) & 1][j] = last_alpha;
      lds_bp[s * 64 + j] = (unsigned char)bnew;   // bp[0] written but unused
    }
    WAIT_LGKM(); __builtin_amdgcn_s_barrier(); CBAR();

    // refill the slot just consumed (own quarter only -> per-wave WAR safe).
    // Past the end we wrap to a valid address; the garbage lands in a slot
    // that is never read again, keeping vmcnt(20) uniform for every step.
    {
      int src = next_src; if (src >= S) src -= S;
      const float* gs = Pb + src * (T * T) + w * 1024 + j * 4;
      float* ls = &lds_p[slot * (T * T) + w * 1024];
#pragma unroll
      for (int r = 0; r < 4; ++r) load16(gs + r * 256, ls + r * 256);
      ++next_src;
    }
    ++slot; if (slot == DEPTH) slot = 0;
  }

  // final argmax over tags (lex: max score, then smallest j), then backtrace
  if (w == 0) {
    unsigned long long mm =
        ((unsigned long long)f2s(last_alpha) << 32) | (unsigned int)(63 - j);
#pragma unroll
    for (int off = 32; off >= 1; off >>= 1) {
      unsigned int hi = (unsigned int)(mm >> 32), lo = (unsigned int)mm;
      unsigned int ohi = __shfl_xor(hi, off, 64);
      unsigned int olo = __shfl_xor(lo, off, 64);
      unsigned long long o = ((unsigned long long)ohi << 32) | olo;
      mm = (o > mm) ? o : mm;
    }
    const int last_tag = 63 - (int)(mm & 0xFFu);
    if (tid == 0) {
      const int* mrow = mask + b * S;
      int* orow = out + b * S;
      int tag = last_tag;
      orow[S - 1] = mrow[S - 1] ? tag : -1;
      for (int s = S - 1; s >= 1; --s) {
        tag = lds_bp[s * 64 + tag];
        orow[s - 1] = mrow[s - 1] ? tag : -1;
      }
    }
  }
  // drain stray wrap-around prefetches before the workgroup's LDS is freed
  WAIT_VM0();
}

} // namespace

extern "C" void kernel_launch(void* const* d_in, const int* in_sizes, int n_in,
                              void* d_out, int out_size, void* d_ws, size_t ws_size,
                              hipStream_t stream) {
  const float* P = (const float*)d_in[0];
  const int* mask = (const int*)d_in[1];
  int* out = (int*)d_out;
  (void)in_sizes; (void)n_in; (void)out_size; (void)d_ws; (void)ws_size;
  hipLaunchKernelGGL(viterbi_fwd, dim3(B), dim3(256), 0, stream, P, mask, out);
}